// Round 13
// baseline (358.330 us; speedup 1.0000x reference)
//
#include <hip/hip_runtime.h>
#include <hip/hip_fp16.h>
#include <cfloat>
#include <cmath>
#include <string.h>

// GNN_Combo pipeline. Round 13: revert to 16-col fingerprint (round 12's
// 32-col doubled rescore work: 67->110us). New: (a) k_gemm folds the key
// epilogue into MFMA (B pre-scaled by -2, acc initialized to sq_col -> key
// = acc, deletes 16 VALU/st/lane); (b) k_filter = list+prefetch structure
// with fused in-wave fp64 rescore + rank -> knn (k_rescore kernel deleted).
// N=16384 nodes, F=64 in-features, H=128 hidden, K=16 neighbors, O=10 classes.

#define N_NODES 16384
#define F_IN    64
#define H_DIM   128
#define K_NN    16
#define O_DIM   10

typedef _Float16 half8  __attribute__((ext_vector_type(8)));
typedef _Float16 half4v __attribute__((ext_vector_type(4)));
typedef _Float16 half2v __attribute__((ext_vector_type(2)));
typedef __fp16   fp16x2 __attribute__((ext_vector_type(2)));
typedef float    floatx4 __attribute__((ext_vector_type(4)));

__device__ __forceinline__ void async_copy16(void* lds, const void* g) {
  __builtin_amdgcn_global_load_lds(
      (const __attribute__((address_space(1))) unsigned int*)g,
      (__attribute__((address_space(3))) unsigned int*)lds, 16, 0, 0);
}

__device__ __forceinline__ unsigned pack2h(float a, float b) {
  half2v p; p[0] = (_Float16)a; p[1] = (_Float16)b;
  unsigned u; __builtin_memcpy(&u, &p, 4); return u;
}
__device__ __forceinline__ float unpacklo(unsigned u) {
  half2v p; __builtin_memcpy(&p, &u, 4); return (float)p[0];
}
__device__ __forceinline__ float unpackhi(unsigned u) {
  half2v p; __builtin_memcpy(&p, &u, 4); return (float)p[1];
}
__device__ __forceinline__ fp16x2 as_h2(unsigned u) {
  fp16x2 p; __builtin_memcpy(&p, &u, 4); return p;
}

// ---------------------------------------------------------------- k_prep ----
__global__ __launch_bounds__(256) void k_prep(const float* __restrict__ x,
                                              float* __restrict__ sq,
                                              double* __restrict__ sq64,
                                              _Float16* __restrict__ xh) {
  const int i = blockIdx.x * 256 + threadIdx.x;
  if (i >= N_NODES) return;
  const float4* r = (const float4*)(x + i * F_IN);
  float s = 0.f; double sd = 0.0;
#pragma unroll
  for (int q = 0; q < 16; ++q) {
    const float4 v = r[q];
    s += v.x*v.x + v.y*v.y + v.z*v.z + v.w*v.w;
    sd += (double)v.x*v.x + (double)v.y*v.y + (double)v.z*v.z + (double)v.w*v.w;
    half4v hv;
    hv[0] = (_Float16)v.x; hv[1] = (_Float16)v.y;
    hv[2] = (_Float16)v.z; hv[3] = (_Float16)v.w;
    *(half4v*)(xh + (size_t)i * F_IN + 4 * q) = hv;
  }
  sq[i] = s; sq64[i] = sd;
}

// ---------------------------------------------------------------- k_gemm ----
// Transposed MFMA, 16-col subtile mins (round 11 output format:
// subg[seg][row][64 B]). Key fused into MFMA: B rows pre-scaled by -2 (exact
// in f16), accumulator initialized to sq_col -> acc IS the key after the two
// MFMAs (no per-element fma epilogue). Stores via LDS transpose (4
// lane-contiguous 1-KB instructions per wave).
__global__ __launch_bounds__(256) void k_gemm(const _Float16* __restrict__ xh,
                                              const float* __restrict__ sq,
                                              char* __restrict__ subg) {
  __shared__ __align__(16) _Float16 stage[128 * 64];  // 16 KB: tiles, then scratch
  __shared__ float sqs[128];
  const int tid = threadIdx.x;
  const int wv = tid >> 6, l = tid & 63;
  const int lane16 = l & 15, quad = l >> 4;
  const int rowblk = (blockIdx.x >> 5) * 256;
  const int seg = blockIdx.x & 31;
  const int rw = rowblk + wv * 64;

  half8 B[4][2];
  half8 neg2;
#pragma unroll
  for (int u = 0; u < 8; ++u) neg2[u] = (_Float16)(-2.0f);
#pragma unroll
  for (int s = 0; s < 4; ++s) {
    const _Float16* bp = xh + (size_t)(rw + s * 16 + lane16) * F_IN + quad * 8;
    B[s][0] = *(const half8*)(bp) * neg2;       // exact scale (power of 2)
    B[s][1] = *(const half8*)(bp + 32) * neg2;
  }

  const int lcol8 = l >> 3;
  const int lchk  = (l & 7) ^ lcol8;
  const size_t lgoff = (size_t)lcol8 * F_IN + lchk * 8;

  unsigned sel[16];   // [tile*4 + pair] -- this lane's row (r_local == l)

#pragma unroll
  for (int tile = 0; tile < 4; ++tile) {
    const int c0 = seg * 512 + tile * 128;
    __syncthreads();
    if (tid < 128) sqs[tid] = sq[c0 + tid];
#pragma unroll
    for (int q = 0; q < 4; ++q) {
      const int grp = wv * 4 + q;
      async_copy16(stage + grp * 512,
                   xh + (size_t)(c0 + grp * 8) * F_IN + lgoff);
    }
    __syncthreads();

    float sprev[4];
    unsigned pk[4][4];
#pragma unroll
    for (int st = 0; st < 8; ++st) {
      const _Float16* base = stage + (st * 16 + lane16) * 64;
      const int sw = lane16 & 7;
      const half8 A0 = *(const half8*)(base + ((quad ^ sw) * 8));
      const half8 A1 = *(const half8*)(base + (((4 + quad) ^ sw) * 8));
      const floatx4 sq4 = *(const floatx4*)(sqs + st * 16 + quad * 4);
      floatx4 acc[4];
#pragma unroll
      for (int s = 0; s < 4; ++s) acc[s] = sq4;   // C init = sq_col
#pragma unroll
      for (int s = 0; s < 4; ++s)
        acc[s] = __builtin_amdgcn_mfma_f32_16x16x32_f16(A0, B[s][0], acc[s], 0, 0, 0);
#pragma unroll
      for (int s = 0; s < 4; ++s)
        acc[s] = __builtin_amdgcn_mfma_f32_16x16x32_f16(A1, B[s][1], acc[s], 0, 0, 0);
#pragma unroll
      for (int s = 0; s < 4; ++s) {
        // acc[s][q] == key(col = st*16+quad*4+q, row = rw+s*16+lane16)
        float m = fminf(fminf(acc[s][0], acc[s][1]), fminf(acc[s][2], acc[s][3]));
        m = fminf(m, __shfl_xor(m, 16, 64));
        m = fminf(m, __shfl_xor(m, 32, 64));
        if ((st & 1) == 0) sprev[s] = m;
        else pk[s][st >> 1] = pack2h(sprev[s], m);
      }
    }
#pragma unroll
    for (int t = 0; t < 4; ++t) {
      unsigned o = pk[0][t];
      if (quad == 1) o = pk[1][t];
      if (quad == 2) o = pk[2][t];
      if (quad == 3) o = pk[3][t];
      sel[tile * 4 + t] = o;
    }
  }
  // ---- LDS transpose -> 4 lane-contiguous 1-KB store instructions ----
  __syncthreads();
  {
    unsigned* sc = (unsigned*)stage + wv * 1024;   // 4 KB per wave
#pragma unroll
    for (int k = 0; k < 16; ++k) sc[k * 64 + l] = sel[k];
    char* dstw = subg + ((size_t)seg * N_NODES + rw) * 64;
#pragma unroll
    for (int t = 0; t < 4; ++t) {
      const int rl = t * 16 + (l >> 2);
      uint4 ov;
      ov.x = sc[((l & 3) * 4 + 0) * 64 + rl];
      ov.y = sc[((l & 3) * 4 + 1) * 64 + rl];
      ov.z = sc[((l & 3) * 4 + 2) * 64 + rl];
      ov.w = sc[((l & 3) * 4 + 3) * 64 + rl];
      *(uint4*)(dstw + t * 1024 + l * 16) = ov;
    }
  }
}

// -------------------------------------------------------------- k_filter ----
// One wave per row, 16-col subtiles (4 lanes/col). Pass 1: compact selected
// subtile ids into per-wave LDS list. Pass 2: counted loop with 1-deep
// gather prefetch; 8 fdot2/lane; passing cols compacted into clist (LDS).
// Phase 3: in-wave fp64 rescore (xi staged in LDS, lane-per-candidate) +
// all-pairs rank-select -> knn. (Replaces the separate k_rescore kernel.)
__global__ __launch_bounds__(256) void k_filter(const _Float16* __restrict__ xh,
                                                const float* __restrict__ sq,
                                                const char* __restrict__ subg,
                                                const float* __restrict__ x,
                                                const double* __restrict__ sq64,
                                                int* __restrict__ knn) {
  __shared__ int    list[4][160];
  __shared__ int    wcnt[4];
  __shared__ int    clist[4][128];
  __shared__ int    ccnt[4];
  __shared__ double kbuf[4][128];
  __shared__ float  xbuf[4][F_IN];
  const int l = threadIdx.x & 63;
  const int wv = threadIdx.x >> 6;
  const int i = blockIdx.x * 4 + wv;
  const int part = l & 3, c = l >> 2;   // 4 lanes per column

  // xi fragment: dims [part*16, part*16+16) as 8 packed f16 pairs
  fp16x2 xi2[8];
  {
    const uint4* xp = (const uint4*)(xh + (size_t)i * F_IN + part * 16);
    const uint4 a = xp[0], b = xp[1];
    xi2[0] = as_h2(a.x); xi2[1] = as_h2(a.y); xi2[2] = as_h2(a.z); xi2[3] = as_h2(a.w);
    xi2[4] = as_h2(b.x); xi2[5] = as_h2(b.y); xi2[6] = as_h2(b.z); xi2[7] = as_h2(b.w);
  }
  // 16 submins for this lane's subtiles [l*16, l*16+16)
  float subs[16];
  {
    const char* sp = subg + ((size_t)(l >> 1) * N_NODES + i) * 64 + (l & 1) * 32;
    const uint4 a = *(const uint4*)(sp);
    const uint4 b = *(const uint4*)(sp + 16);
    subs[0] = unpacklo(a.x); subs[1] = unpackhi(a.x);
    subs[2] = unpacklo(a.y); subs[3] = unpackhi(a.y);
    subs[4] = unpacklo(a.z); subs[5] = unpackhi(a.z);
    subs[6] = unpacklo(a.w); subs[7] = unpackhi(a.w);
    subs[8] = unpacklo(b.x); subs[9] = unpackhi(b.x);
    subs[10] = unpacklo(b.y); subs[11] = unpackhi(b.y);
    subs[12] = unpacklo(b.z); subs[13] = unpackhi(b.z);
    subs[14] = unpacklo(b.w); subs[15] = unpackhi(b.w);
  }
  float cmin = subs[0];
#pragma unroll
  for (int t = 1; t < 16; ++t) cmin = fminf(cmin, subs[t]);
  int rank = 0;
#pragma unroll 4
  for (int j = 0; j < 64; ++j) {
    const float vj = __shfl(cmin, j, 64);
    rank += (vj < cmin) || (vj == cmin && j < l);
  }
  const unsigned long long rm = __ballot(rank == 15);
  const int srcl = __ffsll((long long)rm) - 1;
  const float thr = __shfl(cmin, srcl, 64) + 0.25f;

  unsigned selmask = 0;
#pragma unroll
  for (int t = 0; t < 16; ++t) selmask |= (subs[t] <= thr) ? (1u << t) : 0u;

  // ---- pass 1: compact selected subtile ids into list[wv] ----
  if (l == 0) { wcnt[wv] = 0; ccnt[wv] = 0; }
  __syncthreads();   // barrier 1 (init visible; uniform count per wave)
  int base = 0;
  if (selmask) base = atomicAdd(&wcnt[wv], __popc(selmask));
  {
    unsigned m = selmask; int idx = base;
    while (m) {
      const int b = __ffs(m) - 1; m &= m - 1;
      if (idx < 160) list[wv][idx] = l * 16 + b;   // global subtile id
      ++idx;
    }
  }
  __syncthreads();   // barrier 2 (list complete)
  int n = wcnt[wv]; if (n > 160) n = 160;

  // ---- pass 2: counted loop with 1-deep gather prefetch ----
  uint4 g0a, g0b, g1a, g1b;
  int colc = 0, coln = 0;
  if (n > 0) {
    colc = list[wv][0] * 16;
    const uint4* gp = (const uint4*)(xh + (size_t)(colc + c) * F_IN + part * 16);
    g0a = gp[0]; g0b = gp[1];
  }
  for (int j = 0; j < n; ++j) {
    if (j + 1 < n) {
      coln = list[wv][j + 1] * 16;
      const uint4* gp = (const uint4*)(xh + (size_t)(coln + c) * F_IN + part * 16);
      g1a = gp[0]; g1b = gp[1];
    }
    float d = 0.f;
    d = __builtin_amdgcn_fdot2(xi2[0], as_h2(g0a.x), d, false);
    d = __builtin_amdgcn_fdot2(xi2[1], as_h2(g0a.y), d, false);
    d = __builtin_amdgcn_fdot2(xi2[2], as_h2(g0a.z), d, false);
    d = __builtin_amdgcn_fdot2(xi2[3], as_h2(g0a.w), d, false);
    d = __builtin_amdgcn_fdot2(xi2[4], as_h2(g0b.x), d, false);
    d = __builtin_amdgcn_fdot2(xi2[5], as_h2(g0b.y), d, false);
    d = __builtin_amdgcn_fdot2(xi2[6], as_h2(g0b.z), d, false);
    d = __builtin_amdgcn_fdot2(xi2[7], as_h2(g0b.w), d, false);
    d += __shfl_xor(d, 1, 64);
    d += __shfl_xor(d, 2, 64);
    const int cg = colc + c;
    const float key = fmaf(-2.f, d, sq[cg]);
    const bool pred = (part == 0) && (key <= thr);
    const unsigned long long am = __ballot(pred);
    if (am) {
      const int ldr = __ffsll((long long)am) - 1;
      int cb = 0;
      if (l == ldr) cb = atomicAdd(&ccnt[wv], (int)__popcll(am));
      cb = __shfl(cb, ldr, 64);
      if (pred) {
        const int idx = cb + (int)__popcll(am & ((1ull << l) - 1ull));
        if (idx < 128) clist[wv][idx] = cg;
      }
    }
    colc = coln;
    g0a = g1a; g0b = g1b;
  }
  // stage xi (f32) for the fp64 rescore
  xbuf[wv][l] = x[(size_t)i * F_IN + l];
  __syncthreads();   // barrier 3 (clist + xbuf complete)

  // ---- phase 3: fp64 rescore + rank-select -> knn ----
  int n2 = ccnt[wv]; if (n2 > 128) n2 = 128;
  for (int j = l; j < n2; j += 64) {
    const int id = clist[wv][j];
    const float4* xc4 = (const float4*)(x + (size_t)id * F_IN);
    double d0 = 0.0, d1 = 0.0, d2 = 0.0, d3 = 0.0;
#pragma unroll
    for (int q = 0; q < 16; ++q) {
      const float4 v = xc4[q];
      d0 += (double)xbuf[wv][4*q+0] * (double)v.x;
      d1 += (double)xbuf[wv][4*q+1] * (double)v.y;
      d2 += (double)xbuf[wv][4*q+2] * (double)v.z;
      d3 += (double)xbuf[wv][4*q+3] * (double)v.w;
    }
    kbuf[wv][j] = sq64[id] - 2.0 * ((d0 + d1) + (d2 + d3));
  }
  __syncthreads();   // barrier 4 (kbuf complete)
  for (int j = l; j < n2; j += 64) {
    const double kj = kbuf[wv][j]; const int idj = clist[wv][j];
    int rk = 0;
    for (int t = 0; t < n2; ++t) {
      const double kt = kbuf[wv][t]; const int it = clist[wv][t];
      rk += (kt < kj) || (kt == kj && it < idj);
    }
    if (rk < K_NN) knn[i * K_NN + rk] = idj;
  }
}

// --------------------------------------------------------------- k_lin12 ----
__global__ __launch_bounds__(256, 2) void k_lin12(const float* __restrict__ x,
                                                  const float* __restrict__ w1,
                                                  const float* __restrict__ b1,
                                                  _Float16* __restrict__ Ph,
                                                  _Float16* __restrict__ Qh) {
  __shared__ float wl[2 * F_IN][H_DIM];   // 64 KB
  for (int s = threadIdx.x; s < 2 * F_IN * H_DIM; s += 256) wl[s >> 7][s & 127] = w1[s];
  __syncthreads();
  const int node = blockIdx.x * 32 + (threadIdx.x & 31);
  const int ob = (threadIdx.x >> 5) * 16;
  float accR[16], accQ[16];
#pragma unroll
  for (int o = 0; o < 16; ++o) { accR[o] = 0.f; accQ[o] = 0.f; }
  const float4* xr = (const float4*)(x + node * F_IN);
#define L1STEP(ff, xs) { \
    const float* wt_ = &wl[(ff)][ob]; \
    const float* wb_ = &wl[(ff) + F_IN][ob]; \
    _Pragma("unroll") \
    for (int o = 0; o < 16; o += 4) { \
      const float4 t4 = *(const float4*)(wt_ + o); \
      const float4 b4 = *(const float4*)(wb_ + o); \
      accR[o+0] = fmaf((xs), t4.x, accR[o+0]); accQ[o+0] = fmaf((xs), b4.x, accQ[o+0]); \
      accR[o+1] = fmaf((xs), t4.y, accR[o+1]); accQ[o+1] = fmaf((xs), b4.y, accQ[o+1]); \
      accR[o+2] = fmaf((xs), t4.z, accR[o+2]); accQ[o+2] = fmaf((xs), b4.z, accQ[o+2]); \
      accR[o+3] = fmaf((xs), t4.w, accR[o+3]); accQ[o+3] = fmaf((xs), b4.w, accQ[o+3]); } }
#pragma unroll 2
  for (int q = 0; q < 16; ++q) {
    const float4 xv = xr[q];
    L1STEP(4*q+0, xv.x); L1STEP(4*q+1, xv.y); L1STEP(4*q+2, xv.z); L1STEP(4*q+3, xv.w);
  }
#undef L1STEP
  _Float16* pp = Ph + (size_t)node * H_DIM + ob;
  _Float16* qp = Qh + (size_t)node * H_DIM + ob;
#pragma unroll
  for (int o = 0; o < 16; o += 4) {
    half4v hp, hq;
#pragma unroll
    for (int u = 0; u < 4; ++u) {
      hp[u] = (_Float16)(accR[o+u] - accQ[o+u] + b1[ob + o + u]);
      hq[u] = (_Float16)accQ[o+u];
    }
    *(half4v*)(pp + o) = hp;
    *(half4v*)(qp + o) = hq;
  }
}

// ------------------------------------------------------------ k_edgeconv ----
__global__ __launch_bounds__(256, 2) void k_edgeconv(const _Float16* __restrict__ Ph,
                                                     const _Float16* __restrict__ Qh,
                                                     const float* __restrict__ w2,
                                                     const float* __restrict__ b2,
                                                     const int* __restrict__ knn,
                                                     float* __restrict__ h) {
  __shared__ __align__(16) _Float16 wt[H_DIM * 128];   // 32 KB, swizzled
  __shared__ __align__(16) _Float16 afr[4][2048];      // 16 KB, per-wave A frags
  const int tid = threadIdx.x;
  const int wv = tid >> 6, l = tid & 63;
  const int lane16 = l & 15, quad = l >> 4;

  {
    const int n = tid >> 1, part = tid & 1;
    const float* wsrc = w2 + n;
    _Float16* wdst = wt + n * 128;
#pragma unroll
    for (int c = 0; c < 8; ++c) {
      half8 hv;
#pragma unroll
      for (int u = 0; u < 8; ++u)
        hv[u] = (_Float16)wsrc[(size_t)(part * 64 + c * 8 + u) * H_DIM];
      *(half8*)(wdst + (((part * 8 + c) ^ (n & 15)) * 8)) = hv;
    }
  }
  __syncthreads();

  float b2r[8];
#pragma unroll
  for (int tile = 0; tile < 8; ++tile) b2r[tile] = b2[tile * 16 + lane16];

  const int i0 = blockIdx.x * 32 + wv * 8;
  int js[8];
#pragma unroll
  for (int it = 0; it < 8; ++it) js[it] = knn[(i0 + it) * K_NN + lane16];

  _Float16* aw = afr[wv];
  half8 pc[4], qc[4];
  {
    const half8* pr = (const half8*)(Ph + (size_t)i0 * H_DIM + quad * 32);
    const half8* qr = (const half8*)(Qh + (size_t)js[0] * H_DIM + quad * 32);
#pragma unroll
    for (int c = 0; c < 4; ++c) { pc[c] = pr[c]; qc[c] = qr[c]; }
  }
  for (int it = 0; it < 8; ++it) {
    const int i = i0 + it;
    half8 pn[4], qn[4];
    if (it < 7) {
      const half8* pr = (const half8*)(Ph + (size_t)(i + 1) * H_DIM + quad * 32);
      const half8* qr = (const half8*)(Qh + (size_t)js[it + 1] * H_DIM + quad * 32);
#pragma unroll
      for (int c = 0; c < 4; ++c) { pn[c] = pr[c]; qn[c] = qr[c]; }
    }
#pragma unroll
    for (int c = 0; c < 4; ++c) {
      half8 z = pc[c] + qc[c];
      half8 r;
#pragma unroll
      for (int u = 0; u < 8; ++u) r[u] = z[u] > (_Float16)0 ? z[u] : (_Float16)0;
      *(half8*)(aw + quad * 512 + c * 128 + lane16 * 8) = r;
    }
    half8 A[4];
#pragma unroll
    for (int kb = 0; kb < 4; ++kb) A[kb] = *(const half8*)(aw + kb * 512 + l * 8);
    floatx4 acc[8];
#pragma unroll
    for (int tile = 0; tile < 8; ++tile) acc[tile] = (floatx4)0.f;
#pragma unroll
    for (int kb = 0; kb < 4; ++kb) {
#pragma unroll
      for (int tile = 0; tile < 8; ++tile) {
        const half8 B = *(const half8*)(wt + (tile * 16 + lane16) * 128 +
                                        (((kb * 4 + quad) ^ lane16) * 8));
        acc[tile] = __builtin_amdgcn_mfma_f32_16x16x32_f16(A[kb], B, acc[tile], 0, 0, 0);
      }
    }
    float lse[4];
#pragma unroll
    for (int r = 0; r < 4; ++r) {
      float mx = acc[0][r] + b2r[0];
#pragma unroll
      for (int tile = 1; tile < 8; ++tile) mx = fmaxf(mx, acc[tile][r] + b2r[tile]);
      mx = fmaxf(mx, __shfl_xor(mx, 1, 64));
      mx = fmaxf(mx, __shfl_xor(mx, 2, 64));
      mx = fmaxf(mx, __shfl_xor(mx, 4, 64));
      mx = fmaxf(mx, __shfl_xor(mx, 8, 64));
      float e = 0.f;
#pragma unroll
      for (int tile = 0; tile < 8; ++tile) e += __expf(acc[tile][r] + b2r[tile] - mx);
      e += __shfl_xor(e, 1, 64);
      e += __shfl_xor(e, 2, 64);
      e += __shfl_xor(e, 4, 64);
      e += __shfl_xor(e, 8, 64);
      lse[r] = mx + __logf(e);
    }
#pragma unroll
    for (int tile = 0; tile < 8; ++tile) {
      float v = acc[tile][0] + b2r[tile] - lse[0];
#pragma unroll
      for (int r = 1; r < 4; ++r) v = fmaxf(v, acc[tile][r] + b2r[tile] - lse[r]);
      v = fmaxf(v, __shfl_xor(v, 16, 64));
      v = fmaxf(v, __shfl_xor(v, 32, 64));
      if (quad == 0) h[(size_t)i * H_DIM + tile * 16 + lane16] = v;
    }
#pragma unroll
    for (int c = 0; c < 4; ++c) { pc[c] = pn[c]; qc[c] = qn[c]; }
  }
}

// ----------------------------------------------------------------- k_hw -----
__global__ __launch_bounds__(256) void k_hw(const float* __restrict__ h,
                                            const float* __restrict__ gw,
                                            _Float16* __restrict__ hwh) {
  __shared__ float wl[H_DIM][H_DIM];   // 64 KB
  for (int s = threadIdx.x; s < H_DIM * H_DIM; s += 256) wl[s >> 7][s & 127] = gw[s];
  __syncthreads();
  const int node = blockIdx.x * 32 + (threadIdx.x & 31);
  const int ob = (threadIdx.x >> 5) * 16;
  float acc[16];
#pragma unroll
  for (int o = 0; o < 16; ++o) acc[o] = 0.f;
  const float4* hr = (const float4*)(h + node * H_DIM);
#define HWSTEP(ff, xs) { \
    const float* wr = &wl[(ff)][ob]; \
    _Pragma("unroll") \
    for (int o = 0; o < 16; o += 4) { const float4 w4 = *(const float4*)(wr + o); \
      acc[o+0] = fmaf((xs), w4.x, acc[o+0]); \
      acc[o+1] = fmaf((xs), w4.y, acc[o+1]); \
      acc[o+2] = fmaf((xs), w4.z, acc[o+2]); \
      acc[o+3] = fmaf((xs), w4.w, acc[o+3]); } }
#pragma unroll 2
  for (int q = 0; q < 32; ++q) {
    const float4 hv = hr[q];
    HWSTEP(4*q+0, hv.x); HWSTEP(4*q+1, hv.y); HWSTEP(4*q+2, hv.z); HWSTEP(4*q+3, hv.w);
  }
#undef HWSTEP
  _Float16* dp = hwh + (size_t)node * H_DIM + ob;
#pragma unroll
  for (int o = 0; o < 16; o += 4) {
    half4v hv;
#pragma unroll
    for (int u = 0; u < 4; ++u) hv[u] = (_Float16)acc[o + u];
    *(half4v*)(dp + o) = hv;
  }
}

// --------------------------------------------------------------- k_heads ----
__global__ __launch_bounds__(256) void k_heads(const _Float16* __restrict__ hwh,
                                               const int* __restrict__ knn,
                                               const float* __restrict__ gb,
                                               const float* __restrict__ gow,
                                               const float* __restrict__ gob,
                                               const float* __restrict__ ow,
                                               const float* __restrict__ obv,
                                               float* __restrict__ out) {
  __shared__ unsigned int wgo[H_DIM][64];  // 32 KB
  __shared__ float hbuf[4][H_DIM];         // 2 KB
  for (int s = threadIdx.x; s < H_DIM * 64; s += 256) {
    const int f = s >> 6, l = s & 63;
    wgo[f][l] = pack2h(gow[f * H_DIM + 2 * l], gow[f * H_DIM + 2 * l + 1]);
  }
  __syncthreads();
  const int wv = threadIdx.x >> 6, l = threadIdx.x & 63;
  const unsigned* hw32 = (const unsigned*)hwh;
  const float gbl = gb[2 * l], gbh = gb[2 * l + 1];
  const float gobl = gob[2 * l], gobh = gob[2 * l + 1];
  for (int it = 0; it < 8; ++it) {
    const int i = blockIdx.x * 32 + wv * 8 + it;
    const int* kr = knn + i * K_NN;
    unsigned u = hw32[(size_t)i * 64 + l];
    float s0 = unpacklo(u), s1 = unpackhi(u);
#pragma unroll
    for (int m = 0; m < K_NN; ++m) {
      const unsigned um = hw32[(size_t)kr[m] * 64 + l];
      s0 += unpacklo(um);
      s1 += unpackhi(um);
    }
    const float hg0 = s0 * (1.0f / 17.0f) + gbl;
    const float hg1 = s1 * (1.0f / 17.0f) + gbh;
    hbuf[wv][2 * l] = hg0; hbuf[wv][2 * l + 1] = hg1;
    float z0 = gobl, z1 = gobh;
#pragma unroll 4
    for (int f = 0; f < H_DIM; ++f) {
      const float hv = hbuf[wv][f];
      const unsigned int wvv = wgo[f][l];
      z0 = fmaf(hv, unpacklo(wvv), z0);
      z1 = fmaf(hv, unpackhi(wvv), z1);
    }
    float mx = fmaxf(z0, z1);
#pragma unroll
    for (int s = 1; s < 64; s <<= 1) mx = fmaxf(mx, __shfl_xor(mx, s, 64));
    const float e0 = __expf(z0 - mx), e1 = __expf(z1 - mx);
    float sm = e0 + e1;
#pragma unroll
    for (int s = 1; s < 64; s <<= 1) sm += __shfl_xor(sm, s, 64);
    const float h20 = e0 / sm, h21 = e1 / sm;
    float zc[O_DIM];
#pragma unroll
    for (int c = 0; c < O_DIM; ++c) {
      float a = h20 * ow[(2 * l) * O_DIM + c] + h21 * ow[(2 * l + 1) * O_DIM + c];
#pragma unroll
      for (int s = 1; s < 64; s <<= 1) a += __shfl_xor(a, s, 64);
      zc[c] = a + obv[c];
    }
    float m10 = zc[0];
#pragma unroll
    for (int c = 1; c < O_DIM; ++c) m10 = fmaxf(m10, zc[c]);
    float es[O_DIM]; float s10 = 0.f;
#pragma unroll
    for (int c = 0; c < O_DIM; ++c) { es[c] = __expf(zc[c] - m10); s10 += es[c]; }
    const float inv = 1.0f / s10;
    if (l < O_DIM) {
      float v = es[0];
#pragma unroll
      for (int c = 1; c < O_DIM; ++c) if (l == c) v = es[c];
      out[i * O_DIM + l] = v * inv;
    }
  }
}

// ---------------------------------------------------------------------------
extern "C" void kernel_launch(void* const* d_in, const int* in_sizes, int n_in,
                              void* d_out, int out_size, void* d_ws, size_t ws_size,
                              hipStream_t stream) {
  (void)in_sizes; (void)n_in; (void)out_size; (void)ws_size;
  const float* x   = (const float*)d_in[0];
  const float* w1  = (const float*)d_in[2];
  const float* b1  = (const float*)d_in[3];
  const float* w2  = (const float*)d_in[4];
  const float* b2  = (const float*)d_in[5];
  const float* gw  = (const float*)d_in[6];
  const float* gb  = (const float*)d_in[7];
  const float* gow = (const float*)d_in[8];
  const float* gob = (const float*)d_in[9];
  const float* ow  = (const float*)d_in[10];
  const float* obv = (const float*)d_in[11];
  float* out = (float*)d_out;

  char* ws = (char*)d_ws;
  constexpr size_t MB = 1024 * 1024;
  constexpr size_t OFF_SQ   = 0;                                          // 64 KB
  constexpr size_t OFF_SQ64 = OFF_SQ   + (size_t)N_NODES * 4;             // 128 KB
  constexpr size_t OFF_XH   = OFF_SQ64 + (size_t)N_NODES * 8;             // 2 MB
  constexpr size_t OFF_PQ   = OFF_XH   + (size_t)N_NODES * F_IN * 2;      // 8 MB (Ph+Qh)
  constexpr size_t OFF_SUBG = OFF_PQ   + 8 * MB;                          // 32 MB
  constexpr size_t OFF_KNN  = OFF_SUBG;                                   // 1 MB
  constexpr size_t OFF_H    = OFF_SUBG + 1 * MB;                          // 8 MB f32
  constexpr size_t OFF_HWH  = OFF_SUBG + 9 * MB;                          // 4 MB f16
  float*     sq   = (float*)    (ws + OFF_SQ);
  double*    sq64 = (double*)   (ws + OFF_SQ64);
  _Float16*  xh   = (_Float16*) (ws + OFF_XH);
  char*      subg = (char*)     (ws + OFF_SUBG);
  int*       knn  = (int*)      (ws + OFF_KNN);
  float*     h    = (float*)    (ws + OFF_H);
  _Float16*  hwh  = (_Float16*) (ws + OFF_HWH);
  _Float16*  Ph   = (_Float16*) (ws + OFF_PQ);
  _Float16*  Qh   = (_Float16*) (ws + OFF_PQ + 4 * MB);

  k_prep    <<<N_NODES / 256, 256, 0, stream>>>(x, sq, sq64, xh);
  k_gemm    <<<2048,          256, 0, stream>>>(xh, sq, subg);
  k_filter  <<<N_NODES / 4,   256, 0, stream>>>(xh, sq, subg, x, sq64, knn);
  k_lin12   <<<N_NODES / 32,  256, 0, stream>>>(x, w1, b1, Ph, Qh);
  k_edgeconv<<<N_NODES / 32,  256, 0, stream>>>(Ph, Qh, w2, b2, knn, h);
  k_hw      <<<N_NODES / 32,  256, 0, stream>>>(h, gw, hwh);
  k_heads   <<<N_NODES / 32,  256, 0, stream>>>(hwh, knn, gb, gow, gob, ow, obv, out);
}

// Round 14
// 331.327 us; speedup vs baseline: 1.0815x; 1.0815x over previous
//
#include <hip/hip_runtime.h>
#include <hip/hip_fp16.h>
#include <cfloat>
#include <cmath>
#include <string.h>

// GNN_Combo pipeline. Round 14: keep round-13 k_gemm (key fused into MFMA:
// B pre-scaled by -2, acc init = sq_col); REVERT k_filter to the round-11
// low-VGPR version + separate fp64 k_rescore (round-13 fusion dropped filter
// occupancy 67%->29% and regressed 67->120us).
// N=16384 nodes, F=64 in-features, H=128 hidden, K=16 neighbors, O=10 classes.

#define N_NODES 16384
#define F_IN    64
#define H_DIM   128
#define K_NN    16
#define O_DIM   10

typedef _Float16 half8  __attribute__((ext_vector_type(8)));
typedef _Float16 half4v __attribute__((ext_vector_type(4)));
typedef _Float16 half2v __attribute__((ext_vector_type(2)));
typedef __fp16   fp16x2 __attribute__((ext_vector_type(2)));
typedef float    floatx4 __attribute__((ext_vector_type(4)));

__device__ __forceinline__ void async_copy16(void* lds, const void* g) {
  __builtin_amdgcn_global_load_lds(
      (const __attribute__((address_space(1))) unsigned int*)g,
      (__attribute__((address_space(3))) unsigned int*)lds, 16, 0, 0);
}

__device__ __forceinline__ unsigned pack2h(float a, float b) {
  half2v p; p[0] = (_Float16)a; p[1] = (_Float16)b;
  unsigned u; __builtin_memcpy(&u, &p, 4); return u;
}
__device__ __forceinline__ float unpacklo(unsigned u) {
  half2v p; __builtin_memcpy(&p, &u, 4); return (float)p[0];
}
__device__ __forceinline__ float unpackhi(unsigned u) {
  half2v p; __builtin_memcpy(&p, &u, 4); return (float)p[1];
}
__device__ __forceinline__ fp16x2 as_h2(unsigned u) {
  fp16x2 p; __builtin_memcpy(&p, &u, 4); return p;
}

// ---------------------------------------------------------------- k_prep ----
__global__ __launch_bounds__(256) void k_prep(const float* __restrict__ x,
                                              float* __restrict__ sq,
                                              double* __restrict__ sq64,
                                              _Float16* __restrict__ xh,
                                              unsigned* __restrict__ cnt) {
  const int i = blockIdx.x * 256 + threadIdx.x;
  if (i >= N_NODES) return;
  const float4* r = (const float4*)(x + i * F_IN);
  float s = 0.f; double sd = 0.0;
#pragma unroll
  for (int q = 0; q < 16; ++q) {
    const float4 v = r[q];
    s += v.x*v.x + v.y*v.y + v.z*v.z + v.w*v.w;
    sd += (double)v.x*v.x + (double)v.y*v.y + (double)v.z*v.z + (double)v.w*v.w;
    half4v hv;
    hv[0] = (_Float16)v.x; hv[1] = (_Float16)v.y;
    hv[2] = (_Float16)v.z; hv[3] = (_Float16)v.w;
    *(half4v*)(xh + (size_t)i * F_IN + 4 * q) = hv;
  }
  sq[i] = s; sq64[i] = sd; cnt[i] = 0;
}

// ---------------------------------------------------------------- k_gemm ----
// Transposed MFMA, 16-col subtile mins, subg[seg][row][64 B]. Key fused into
// MFMA: B pre-scaled by -2 (exact), acc init = sq_col -> acc IS the key.
// Stores via LDS transpose (4 lane-contiguous 1-KB instructions per wave).
__global__ __launch_bounds__(256) void k_gemm(const _Float16* __restrict__ xh,
                                              const float* __restrict__ sq,
                                              char* __restrict__ subg) {
  __shared__ __align__(16) _Float16 stage[128 * 64];  // 16 KB: tiles, then scratch
  __shared__ float sqs[128];
  const int tid = threadIdx.x;
  const int wv = tid >> 6, l = tid & 63;
  const int lane16 = l & 15, quad = l >> 4;
  const int rowblk = (blockIdx.x >> 5) * 256;
  const int seg = blockIdx.x & 31;
  const int rw = rowblk + wv * 64;

  half8 B[4][2];
  half8 neg2;
#pragma unroll
  for (int u = 0; u < 8; ++u) neg2[u] = (_Float16)(-2.0f);
#pragma unroll
  for (int s = 0; s < 4; ++s) {
    const _Float16* bp = xh + (size_t)(rw + s * 16 + lane16) * F_IN + quad * 8;
    B[s][0] = *(const half8*)(bp) * neg2;       // exact scale (power of 2)
    B[s][1] = *(const half8*)(bp + 32) * neg2;
  }

  const int lcol8 = l >> 3;
  const int lchk  = (l & 7) ^ lcol8;
  const size_t lgoff = (size_t)lcol8 * F_IN + lchk * 8;

  unsigned sel[16];   // [tile*4 + pair] -- this lane's row (r_local == l)

#pragma unroll
  for (int tile = 0; tile < 4; ++tile) {
    const int c0 = seg * 512 + tile * 128;
    __syncthreads();
    if (tid < 128) sqs[tid] = sq[c0 + tid];
#pragma unroll
    for (int q = 0; q < 4; ++q) {
      const int grp = wv * 4 + q;
      async_copy16(stage + grp * 512,
                   xh + (size_t)(c0 + grp * 8) * F_IN + lgoff);
    }
    __syncthreads();

    float sprev[4];
    unsigned pk[4][4];
#pragma unroll
    for (int st = 0; st < 8; ++st) {
      const _Float16* base = stage + (st * 16 + lane16) * 64;
      const int sw = lane16 & 7;
      const half8 A0 = *(const half8*)(base + ((quad ^ sw) * 8));
      const half8 A1 = *(const half8*)(base + (((4 + quad) ^ sw) * 8));
      const floatx4 sq4 = *(const floatx4*)(sqs + st * 16 + quad * 4);
      floatx4 acc[4];
#pragma unroll
      for (int s = 0; s < 4; ++s) acc[s] = sq4;   // C init = sq_col
#pragma unroll
      for (int s = 0; s < 4; ++s)
        acc[s] = __builtin_amdgcn_mfma_f32_16x16x32_f16(A0, B[s][0], acc[s], 0, 0, 0);
#pragma unroll
      for (int s = 0; s < 4; ++s)
        acc[s] = __builtin_amdgcn_mfma_f32_16x16x32_f16(A1, B[s][1], acc[s], 0, 0, 0);
#pragma unroll
      for (int s = 0; s < 4; ++s) {
        float m = fminf(fminf(acc[s][0], acc[s][1]), fminf(acc[s][2], acc[s][3]));
        m = fminf(m, __shfl_xor(m, 16, 64));
        m = fminf(m, __shfl_xor(m, 32, 64));
        if ((st & 1) == 0) sprev[s] = m;
        else pk[s][st >> 1] = pack2h(sprev[s], m);
      }
    }
#pragma unroll
    for (int t = 0; t < 4; ++t) {
      unsigned o = pk[0][t];
      if (quad == 1) o = pk[1][t];
      if (quad == 2) o = pk[2][t];
      if (quad == 3) o = pk[3][t];
      sel[tile * 4 + t] = o;
    }
  }
  // ---- LDS transpose -> 4 lane-contiguous 1-KB store instructions ----
  __syncthreads();
  {
    unsigned* sc = (unsigned*)stage + wv * 1024;   // 4 KB per wave
#pragma unroll
    for (int k = 0; k < 16; ++k) sc[k * 64 + l] = sel[k];
    char* dstw = subg + ((size_t)seg * N_NODES + rw) * 64;
#pragma unroll
    for (int t = 0; t < 4; ++t) {
      const int rl = t * 16 + (l >> 2);
      uint4 ov;
      ov.x = sc[((l & 3) * 4 + 0) * 64 + rl];
      ov.y = sc[((l & 3) * 4 + 1) * 64 + rl];
      ov.z = sc[((l & 3) * 4 + 2) * 64 + rl];
      ov.w = sc[((l & 3) * 4 + 3) * 64 + rl];
      *(uint4*)(dstw + t * 1024 + l * 16) = ov;
    }
  }
}

// -------------------------------------------------------------- k_filter ----
// Round-11 version: one wave per row, fdot2 dots, nested-while over selected
// subtiles, global-atomic compacted candidate append. 20 VGPRs -> 67% occ.
__global__ __launch_bounds__(256) void k_filter(const _Float16* __restrict__ xh,
                                                const float* __restrict__ sq,
                                                const char* __restrict__ subg,
                                                unsigned* __restrict__ cnt,
                                                int* __restrict__ cand) {
  const int l = threadIdx.x & 63;
  const int i = blockIdx.x * 4 + (threadIdx.x >> 6);
  const int part = l & 3, c = l >> 2;

  fp16x2 xi2[8];
  {
    const uint4* xp = (const uint4*)(xh + (size_t)i * F_IN + part * 16);
    const uint4 a = xp[0], b = xp[1];
    xi2[0] = as_h2(a.x); xi2[1] = as_h2(a.y); xi2[2] = as_h2(a.z); xi2[3] = as_h2(a.w);
    xi2[4] = as_h2(b.x); xi2[5] = as_h2(b.y); xi2[6] = as_h2(b.z); xi2[7] = as_h2(b.w);
  }
  float subs[16];
  {
    const char* sp = subg + ((size_t)(l >> 1) * N_NODES + i) * 64 + (l & 1) * 32;
    const uint4 a = *(const uint4*)(sp);
    const uint4 b = *(const uint4*)(sp + 16);
    subs[0] = unpacklo(a.x); subs[1] = unpackhi(a.x);
    subs[2] = unpacklo(a.y); subs[3] = unpackhi(a.y);
    subs[4] = unpacklo(a.z); subs[5] = unpackhi(a.z);
    subs[6] = unpacklo(a.w); subs[7] = unpackhi(a.w);
    subs[8] = unpacklo(b.x); subs[9] = unpackhi(b.x);
    subs[10] = unpacklo(b.y); subs[11] = unpackhi(b.y);
    subs[12] = unpacklo(b.z); subs[13] = unpackhi(b.z);
    subs[14] = unpacklo(b.w); subs[15] = unpackhi(b.w);
  }
  float cmin = subs[0];
#pragma unroll
  for (int t = 1; t < 16; ++t) cmin = fminf(cmin, subs[t]);
  int rank = 0;
#pragma unroll 4
  for (int j = 0; j < 64; ++j) {
    const float vj = __shfl(cmin, j, 64);
    rank += (vj < cmin) || (vj == cmin && j < l);
  }
  const unsigned long long rm = __ballot(rank == 15);
  const int srcl = __ffsll((long long)rm) - 1;
  const float thr = __shfl(cmin, srcl, 64) + 0.25f;

  unsigned selmask = 0;
#pragma unroll
  for (int t = 0; t < 16; ++t) selmask |= (subs[t] <= thr) ? (1u << t) : 0u;

  unsigned long long act;
  while ((act = __ballot(selmask != 0)) != 0ull) {
    const int src = __ffsll((long long)act) - 1;
    unsigned m = __shfl(selmask, src, 64);
    if (l == src) selmask = 0;
    while (m) {
      const int b = __ffs(m) - 1; m &= m - 1;
      const int sid = src * 16 + b;
      const int cg = sid * 16 + c;
      float d = 0.f;
      {
        const uint4* gp = (const uint4*)(xh + (size_t)cg * F_IN + part * 16);
        const uint4 g0 = gp[0], g1 = gp[1];
        d = __builtin_amdgcn_fdot2(xi2[0], as_h2(g0.x), d, false);
        d = __builtin_amdgcn_fdot2(xi2[1], as_h2(g0.y), d, false);
        d = __builtin_amdgcn_fdot2(xi2[2], as_h2(g0.z), d, false);
        d = __builtin_amdgcn_fdot2(xi2[3], as_h2(g0.w), d, false);
        d = __builtin_amdgcn_fdot2(xi2[4], as_h2(g1.x), d, false);
        d = __builtin_amdgcn_fdot2(xi2[5], as_h2(g1.y), d, false);
        d = __builtin_amdgcn_fdot2(xi2[6], as_h2(g1.z), d, false);
        d = __builtin_amdgcn_fdot2(xi2[7], as_h2(g1.w), d, false);
      }
      d += __shfl_xor(d, 1, 64);
      d += __shfl_xor(d, 2, 64);
      const float key = fmaf(-2.f, d, sq[cg]);
      const bool pred = (part == 0) && (key <= thr);
      const unsigned long long am = __ballot(pred);
      if (am) {
        const int ldr = __ffsll((long long)am) - 1;
        unsigned base = 0;
        if (l == ldr) base = atomicAdd(&cnt[i], (unsigned)__popcll(am));
        base = __shfl(base, ldr, 64);
        if (pred) {
          const unsigned idx = base + (unsigned)__popcll(am & ((1ull << l) - 1ull));
          if (idx < 128u) cand[(size_t)i * 128 + idx] = cg;
        }
      }
    }
  }
}

// ------------------------------------------------------------- k_rescore ----
__global__ __launch_bounds__(128) void k_rescore(const float* __restrict__ x,
                                                 const double* __restrict__ sq64,
                                                 const int* __restrict__ cand,
                                                 const unsigned* __restrict__ cnt,
                                                 int* __restrict__ knn) {
  __shared__ float  xi[F_IN];
  __shared__ double keys[128];
  __shared__ int    ids[128];
  const int i = blockIdx.x, t = threadIdx.x;
  const unsigned cv = cnt[i];
  const int n = (int)(cv < 128u ? cv : 128u);
  if (t < F_IN) xi[t] = x[i * F_IN + t];
  __syncthreads();
  double key = 1e300; int id = 0x7fffffff;
  if (t < n) {
    id = cand[(size_t)i * 128 + t];
    const float4* xc4 = (const float4*)(x + (size_t)id * F_IN);
    double d0 = 0.0, d1 = 0.0, d2 = 0.0, d3 = 0.0;
#pragma unroll
    for (int q = 0; q < 16; ++q) {
      const float4 v = xc4[q];
      d0 += (double)xi[4*q+0] * (double)v.x;
      d1 += (double)xi[4*q+1] * (double)v.y;
      d2 += (double)xi[4*q+2] * (double)v.z;
      d3 += (double)xi[4*q+3] * (double)v.w;
    }
    key = sq64[id] - 2.0 * ((d0 + d1) + (d2 + d3));
  }
  keys[t] = key; ids[t] = id;
  __syncthreads();
  int rank = 0;
  for (int cix = 0; cix < n; ++cix) {
    const double kc = keys[cix]; const int ic = ids[cix];
    rank += (kc < key) || (kc == key && ic < id);
  }
  if (t < n && rank < K_NN) knn[i * K_NN + rank] = id;
}

// --------------------------------------------------------------- k_lin12 ----
__global__ __launch_bounds__(256, 2) void k_lin12(const float* __restrict__ x,
                                                  const float* __restrict__ w1,
                                                  const float* __restrict__ b1,
                                                  _Float16* __restrict__ Ph,
                                                  _Float16* __restrict__ Qh) {
  __shared__ float wl[2 * F_IN][H_DIM];   // 64 KB
  for (int s = threadIdx.x; s < 2 * F_IN * H_DIM; s += 256) wl[s >> 7][s & 127] = w1[s];
  __syncthreads();
  const int node = blockIdx.x * 32 + (threadIdx.x & 31);
  const int ob = (threadIdx.x >> 5) * 16;
  float accR[16], accQ[16];
#pragma unroll
  for (int o = 0; o < 16; ++o) { accR[o] = 0.f; accQ[o] = 0.f; }
  const float4* xr = (const float4*)(x + node * F_IN);
#define L1STEP(ff, xs) { \
    const float* wt_ = &wl[(ff)][ob]; \
    const float* wb_ = &wl[(ff) + F_IN][ob]; \
    _Pragma("unroll") \
    for (int o = 0; o < 16; o += 4) { \
      const float4 t4 = *(const float4*)(wt_ + o); \
      const float4 b4 = *(const float4*)(wb_ + o); \
      accR[o+0] = fmaf((xs), t4.x, accR[o+0]); accQ[o+0] = fmaf((xs), b4.x, accQ[o+0]); \
      accR[o+1] = fmaf((xs), t4.y, accR[o+1]); accQ[o+1] = fmaf((xs), b4.y, accQ[o+1]); \
      accR[o+2] = fmaf((xs), t4.z, accR[o+2]); accQ[o+2] = fmaf((xs), b4.z, accQ[o+2]); \
      accR[o+3] = fmaf((xs), t4.w, accR[o+3]); accQ[o+3] = fmaf((xs), b4.w, accQ[o+3]); } }
#pragma unroll 2
  for (int q = 0; q < 16; ++q) {
    const float4 xv = xr[q];
    L1STEP(4*q+0, xv.x); L1STEP(4*q+1, xv.y); L1STEP(4*q+2, xv.z); L1STEP(4*q+3, xv.w);
  }
#undef L1STEP
  _Float16* pp = Ph + (size_t)node * H_DIM + ob;
  _Float16* qp = Qh + (size_t)node * H_DIM + ob;
#pragma unroll
  for (int o = 0; o < 16; o += 4) {
    half4v hp, hq;
#pragma unroll
    for (int u = 0; u < 4; ++u) {
      hp[u] = (_Float16)(accR[o+u] - accQ[o+u] + b1[ob + o + u]);
      hq[u] = (_Float16)accQ[o+u];
    }
    *(half4v*)(pp + o) = hp;
    *(half4v*)(qp + o) = hq;
  }
}

// ------------------------------------------------------------ k_edgeconv ----
__global__ __launch_bounds__(256, 2) void k_edgeconv(const _Float16* __restrict__ Ph,
                                                     const _Float16* __restrict__ Qh,
                                                     const float* __restrict__ w2,
                                                     const float* __restrict__ b2,
                                                     const int* __restrict__ knn,
                                                     float* __restrict__ h) {
  __shared__ __align__(16) _Float16 wt[H_DIM * 128];   // 32 KB, swizzled
  __shared__ __align__(16) _Float16 afr[4][2048];      // 16 KB, per-wave A frags
  const int tid = threadIdx.x;
  const int wv = tid >> 6, l = tid & 63;
  const int lane16 = l & 15, quad = l >> 4;

  {
    const int n = tid >> 1, part = tid & 1;
    const float* wsrc = w2 + n;
    _Float16* wdst = wt + n * 128;
#pragma unroll
    for (int c = 0; c < 8; ++c) {
      half8 hv;
#pragma unroll
      for (int u = 0; u < 8; ++u)
        hv[u] = (_Float16)wsrc[(size_t)(part * 64 + c * 8 + u) * H_DIM];
      *(half8*)(wdst + (((part * 8 + c) ^ (n & 15)) * 8)) = hv;
    }
  }
  __syncthreads();

  float b2r[8];
#pragma unroll
  for (int tile = 0; tile < 8; ++tile) b2r[tile] = b2[tile * 16 + lane16];

  const int i0 = blockIdx.x * 32 + wv * 8;
  int js[8];
#pragma unroll
  for (int it = 0; it < 8; ++it) js[it] = knn[(i0 + it) * K_NN + lane16];

  _Float16* aw = afr[wv];
  half8 pc[4], qc[4];
  {
    const half8* pr = (const half8*)(Ph + (size_t)i0 * H_DIM + quad * 32);
    const half8* qr = (const half8*)(Qh + (size_t)js[0] * H_DIM + quad * 32);
#pragma unroll
    for (int c = 0; c < 4; ++c) { pc[c] = pr[c]; qc[c] = qr[c]; }
  }
  for (int it = 0; it < 8; ++it) {
    const int i = i0 + it;
    half8 pn[4], qn[4];
    if (it < 7) {
      const half8* pr = (const half8*)(Ph + (size_t)(i + 1) * H_DIM + quad * 32);
      const half8* qr = (const half8*)(Qh + (size_t)js[it + 1] * H_DIM + quad * 32);
#pragma unroll
      for (int c = 0; c < 4; ++c) { pn[c] = pr[c]; qn[c] = qr[c]; }
    }
#pragma unroll
    for (int c = 0; c < 4; ++c) {
      half8 z = pc[c] + qc[c];
      half8 r;
#pragma unroll
      for (int u = 0; u < 8; ++u) r[u] = z[u] > (_Float16)0 ? z[u] : (_Float16)0;
      *(half8*)(aw + quad * 512 + c * 128 + lane16 * 8) = r;
    }
    half8 A[4];
#pragma unroll
    for (int kb = 0; kb < 4; ++kb) A[kb] = *(const half8*)(aw + kb * 512 + l * 8);
    floatx4 acc[8];
#pragma unroll
    for (int tile = 0; tile < 8; ++tile) acc[tile] = (floatx4)0.f;
#pragma unroll
    for (int kb = 0; kb < 4; ++kb) {
#pragma unroll
      for (int tile = 0; tile < 8; ++tile) {
        const half8 B = *(const half8*)(wt + (tile * 16 + lane16) * 128 +
                                        (((kb * 4 + quad) ^ lane16) * 8));
        acc[tile] = __builtin_amdgcn_mfma_f32_16x16x32_f16(A[kb], B, acc[tile], 0, 0, 0);
      }
    }
    float lse[4];
#pragma unroll
    for (int r = 0; r < 4; ++r) {
      float mx = acc[0][r] + b2r[0];
#pragma unroll
      for (int tile = 1; tile < 8; ++tile) mx = fmaxf(mx, acc[tile][r] + b2r[tile]);
      mx = fmaxf(mx, __shfl_xor(mx, 1, 64));
      mx = fmaxf(mx, __shfl_xor(mx, 2, 64));
      mx = fmaxf(mx, __shfl_xor(mx, 4, 64));
      mx = fmaxf(mx, __shfl_xor(mx, 8, 64));
      float e = 0.f;
#pragma unroll
      for (int tile = 0; tile < 8; ++tile) e += __expf(acc[tile][r] + b2r[tile] - mx);
      e += __shfl_xor(e, 1, 64);
      e += __shfl_xor(e, 2, 64);
      e += __shfl_xor(e, 4, 64);
      e += __shfl_xor(e, 8, 64);
      lse[r] = mx + __logf(e);
    }
#pragma unroll
    for (int tile = 0; tile < 8; ++tile) {
      float v = acc[tile][0] + b2r[tile] - lse[0];
#pragma unroll
      for (int r = 1; r < 4; ++r) v = fmaxf(v, acc[tile][r] + b2r[tile] - lse[r]);
      v = fmaxf(v, __shfl_xor(v, 16, 64));
      v = fmaxf(v, __shfl_xor(v, 32, 64));
      if (quad == 0) h[(size_t)i * H_DIM + tile * 16 + lane16] = v;
    }
#pragma unroll
    for (int c = 0; c < 4; ++c) { pc[c] = pn[c]; qc[c] = qn[c]; }
  }
}

// ----------------------------------------------------------------- k_hw -----
__global__ __launch_bounds__(256) void k_hw(const float* __restrict__ h,
                                            const float* __restrict__ gw,
                                            _Float16* __restrict__ hwh) {
  __shared__ float wl[H_DIM][H_DIM];   // 64 KB
  for (int s = threadIdx.x; s < H_DIM * H_DIM; s += 256) wl[s >> 7][s & 127] = gw[s];
  __syncthreads();
  const int node = blockIdx.x * 32 + (threadIdx.x & 31);
  const int ob = (threadIdx.x >> 5) * 16;
  float acc[16];
#pragma unroll
  for (int o = 0; o < 16; ++o) acc[o] = 0.f;
  const float4* hr = (const float4*)(h + node * H_DIM);
#define HWSTEP(ff, xs) { \
    const float* wr = &wl[(ff)][ob]; \
    _Pragma("unroll") \
    for (int o = 0; o < 16; o += 4) { const float4 w4 = *(const float4*)(wr + o); \
      acc[o+0] = fmaf((xs), w4.x, acc[o+0]); \
      acc[o+1] = fmaf((xs), w4.y, acc[o+1]); \
      acc[o+2] = fmaf((xs), w4.z, acc[o+2]); \
      acc[o+3] = fmaf((xs), w4.w, acc[o+3]); } }
#pragma unroll 2
  for (int q = 0; q < 32; ++q) {
    const float4 hv = hr[q];
    HWSTEP(4*q+0, hv.x); HWSTEP(4*q+1, hv.y); HWSTEP(4*q+2, hv.z); HWSTEP(4*q+3, hv.w);
  }
#undef HWSTEP
  _Float16* dp = hwh + (size_t)node * H_DIM + ob;
#pragma unroll
  for (int o = 0; o < 16; o += 4) {
    half4v hv;
#pragma unroll
    for (int u = 0; u < 4; ++u) hv[u] = (_Float16)acc[o + u];
    *(half4v*)(dp + o) = hv;
  }
}

// --------------------------------------------------------------- k_heads ----
__global__ __launch_bounds__(256) void k_heads(const _Float16* __restrict__ hwh,
                                               const int* __restrict__ knn,
                                               const float* __restrict__ gb,
                                               const float* __restrict__ gow,
                                               const float* __restrict__ gob,
                                               const float* __restrict__ ow,
                                               const float* __restrict__ obv,
                                               float* __restrict__ out) {
  __shared__ unsigned int wgo[H_DIM][64];  // 32 KB
  __shared__ float hbuf[4][H_DIM];         // 2 KB
  for (int s = threadIdx.x; s < H_DIM * 64; s += 256) {
    const int f = s >> 6, l = s & 63;
    wgo[f][l] = pack2h(gow[f * H_DIM + 2 * l], gow[f * H_DIM + 2 * l + 1]);
  }
  __syncthreads();
  const int wv = threadIdx.x >> 6, l = threadIdx.x & 63;
  const unsigned* hw32 = (const unsigned*)hwh;
  const float gbl = gb[2 * l], gbh = gb[2 * l + 1];
  const float gobl = gob[2 * l], gobh = gob[2 * l + 1];
  for (int it = 0; it < 8; ++it) {
    const int i = blockIdx.x * 32 + wv * 8 + it;
    const int* kr = knn + i * K_NN;
    unsigned u = hw32[(size_t)i * 64 + l];
    float s0 = unpacklo(u), s1 = unpackhi(u);
#pragma unroll
    for (int m = 0; m < K_NN; ++m) {
      const unsigned um = hw32[(size_t)kr[m] * 64 + l];
      s0 += unpacklo(um);
      s1 += unpackhi(um);
    }
    const float hg0 = s0 * (1.0f / 17.0f) + gbl;
    const float hg1 = s1 * (1.0f / 17.0f) + gbh;
    hbuf[wv][2 * l] = hg0; hbuf[wv][2 * l + 1] = hg1;
    float z0 = gobl, z1 = gobh;
#pragma unroll 4
    for (int f = 0; f < H_DIM; ++f) {
      const float hv = hbuf[wv][f];
      const unsigned int wvv = wgo[f][l];
      z0 = fmaf(hv, unpacklo(wvv), z0);
      z1 = fmaf(hv, unpackhi(wvv), z1);
    }
    float mx = fmaxf(z0, z1);
#pragma unroll
    for (int s = 1; s < 64; s <<= 1) mx = fmaxf(mx, __shfl_xor(mx, s, 64));
    const float e0 = __expf(z0 - mx), e1 = __expf(z1 - mx);
    float sm = e0 + e1;
#pragma unroll
    for (int s = 1; s < 64; s <<= 1) sm += __shfl_xor(sm, s, 64);
    const float h20 = e0 / sm, h21 = e1 / sm;
    float zc[O_DIM];
#pragma unroll
    for (int c = 0; c < O_DIM; ++c) {
      float a = h20 * ow[(2 * l) * O_DIM + c] + h21 * ow[(2 * l + 1) * O_DIM + c];
#pragma unroll
      for (int s = 1; s < 64; s <<= 1) a += __shfl_xor(a, s, 64);
      zc[c] = a + obv[c];
    }
    float m10 = zc[0];
#pragma unroll
    for (int c = 1; c < O_DIM; ++c) m10 = fmaxf(m10, zc[c]);
    float es[O_DIM]; float s10 = 0.f;
#pragma unroll
    for (int c = 0; c < O_DIM; ++c) { es[c] = __expf(zc[c] - m10); s10 += es[c]; }
    const float inv = 1.0f / s10;
    if (l < O_DIM) {
      float v = es[0];
#pragma unroll
      for (int c = 1; c < O_DIM; ++c) if (l == c) v = es[c];
      out[i * O_DIM + l] = v * inv;
    }
  }
}

// ---------------------------------------------------------------------------
extern "C" void kernel_launch(void* const* d_in, const int* in_sizes, int n_in,
                              void* d_out, int out_size, void* d_ws, size_t ws_size,
                              hipStream_t stream) {
  (void)in_sizes; (void)n_in; (void)out_size; (void)ws_size;
  const float* x   = (const float*)d_in[0];
  const float* w1  = (const float*)d_in[2];
  const float* b1  = (const float*)d_in[3];
  const float* w2  = (const float*)d_in[4];
  const float* b2  = (const float*)d_in[5];
  const float* gw  = (const float*)d_in[6];
  const float* gb  = (const float*)d_in[7];
  const float* gow = (const float*)d_in[8];
  const float* gob = (const float*)d_in[9];
  const float* ow  = (const float*)d_in[10];
  const float* obv = (const float*)d_in[11];
  float* out = (float*)d_out;

  char* ws = (char*)d_ws;
  constexpr size_t MB = 1024 * 1024;
  constexpr size_t OFF_SQ   = 0;                                          // 64 KB
  constexpr size_t OFF_SQ64 = OFF_SQ   + (size_t)N_NODES * 4;             // 128 KB
  constexpr size_t OFF_XH   = OFF_SQ64 + (size_t)N_NODES * 8;             // 2 MB
  constexpr size_t OFF_CNT  = OFF_XH   + (size_t)N_NODES * F_IN * 2;      // 64 KB
  constexpr size_t OFF_CAND = OFF_CNT  + (size_t)N_NODES * 4;             // 8 MB
  constexpr size_t OFF_SUBG = OFF_CAND + (size_t)N_NODES * 128 * 4;       // 32 MB
  constexpr size_t OFF_KNN  = OFF_SUBG;                                   // 1 MB
  constexpr size_t OFF_H    = OFF_SUBG + 1 * MB;                          // 8 MB f32
  constexpr size_t OFF_HWH  = OFF_SUBG + 9 * MB;                          // 4 MB f16
  float*     sq   = (float*)    (ws + OFF_SQ);
  double*    sq64 = (double*)   (ws + OFF_SQ64);
  _Float16*  xh   = (_Float16*) (ws + OFF_XH);
  unsigned*  cnt  = (unsigned*) (ws + OFF_CNT);
  int*       cand = (int*)      (ws + OFF_CAND);
  char*      subg = (char*)     (ws + OFF_SUBG);
  int*       knn  = (int*)      (ws + OFF_KNN);
  float*     h    = (float*)    (ws + OFF_H);
  _Float16*  hwh  = (_Float16*) (ws + OFF_HWH);
  _Float16*  Ph   = (_Float16*) (ws + OFF_CAND);
  _Float16*  Qh   = (_Float16*) (ws + OFF_CAND + 4 * MB);

  k_prep    <<<N_NODES / 256, 256, 0, stream>>>(x, sq, sq64, xh, cnt);
  k_gemm    <<<2048,          256, 0, stream>>>(xh, sq, subg);
  k_filter  <<<N_NODES / 4,   256, 0, stream>>>(xh, sq, subg, cnt, cand);
  k_rescore <<<N_NODES,       128, 0, stream>>>(x, sq64, cand, cnt, knn);
  k_lin12   <<<N_NODES / 32,  256, 0, stream>>>(x, w1, b1, Ph, Qh);
  k_edgeconv<<<N_NODES / 32,  256, 0, stream>>>(Ph, Qh, w2, b2, knn, h);
  k_hw      <<<N_NODES / 32,  256, 0, stream>>>(h, gw, hwh);
  k_heads   <<<N_NODES / 32,  256, 0, stream>>>(hwh, knn, gb, gow, gob, ow, obv, out);
}